// Round 1
// baseline (211.330 us; speedup 1.0000x reference)
//
#include <hip/hip_runtime.h>
#include <hip/hip_bf16.h>
#include <cstdint>

// Problem constants
#define NWORDS 16384   // B*S
#define NCH    20      // chars per word (NC)
#define CEDIM  32      // char emb dim (CE)
#define WEDIM  512     // output channels (WE)
#define TPOS   17      // conv output positions = NC-KS+1
#define WPB    7       // words per block
#define ROWS   (WPB*TPOS)   // 119 im2col rows per block
#define BK     128     // K dim (i<32 only; lang-bit row folded into bias)
#define BN     128     // channels per block
#define NWG    2341    // ceil(16384/7)

typedef __attribute__((ext_vector_type(8))) short bf16x8;
typedef __attribute__((ext_vector_type(4))) float f32x4;

__device__ __forceinline__ unsigned short f2bf(float f){
    union { float f; unsigned int u; } v; v.f = f;
    unsigned int u = v.u + 0x7fffu + ((v.u >> 16) & 1u);
    return (unsigned short)(u >> 16);
}

// Pre-kernel: W' [512][128] bf16 (kk = i*4+k, i<32) + bias[o] = sum_k W[o][32][k]
__global__ __launch_bounds__(256) void prep_kernel(const float* __restrict__ cnn,
                                                   unsigned short* __restrict__ wbf,
                                                   float* __restrict__ bias){
    int idx = blockIdx.x * 256 + threadIdx.x;
    if (idx < WEDIM*BK){
        int o = idx >> 7, kk = idx & 127;
        wbf[idx] = f2bf(cnn[o*132 + kk]);
    } else if (idx < WEDIM*BK + WEDIM){
        int o = idx - WEDIM*BK;
        const float* p = cnn + o*132 + 128;
        bias[o] = p[0] + p[1] + p[2] + p[3];
    }
}

__global__ __launch_bounds__(256, 2) void conv_kernel(
    const float* __restrict__ cemb,          // [256][32] f32
    const int* __restrict__ data,            // [16384]
    const int* __restrict__ spelling,        // [50000][20]
    const unsigned short* __restrict__ wbf,  // [512][128] bf16
    const float* __restrict__ bias,          // [512]
    float* __restrict__ out)                 // [16384][512] f32
{
    __shared__ __align__(16) char smem[65536];
    float* sX   = (float*)(smem + 32768);          // 17920 B, overlays sW region
    int*   scid = (int*)(smem + 32768 + 17920);    // 560 B
    float* sY   = (float*)smem;                    // 60928 B, overlays everything

    const int tid    = threadIdx.x;
    const int wg     = blockIdx.x >> 2;
    const int chbase = (blockIdx.x & 3) << 7;
    const int wbase  = wg * WPB;

    // ---- phase 1: char ids for the block's 7 words ----
    if (tid < WPB*NCH){
        int w = tid / NCH;
        int j = tid - w*NCH;
        int gw = wbase + w;
        int word = (gw < NWORDS) ? data[gw] : 0;
        scid[tid] = spelling[word*NCH + j];
    }
    __syncthreads();

    // ---- phase 2: sX[w][i][j] = cemb[cid[w][j]][i] (f32) ----
    for (int s = tid; s < WPB*CEDIM*NCH; s += 256){
        int w = s / (CEDIM*NCH);
        int r = s - w*(CEDIM*NCH);
        int i = r & 31;
        int j = r >> 5;
        sX[(w*CEDIM + i)*NCH + j] = cemb[scid[w*NCH + j]*CEDIM + i];
    }
    __syncthreads();

    // ---- phase 3: build im2col sA [119][128] bf16, XOR-swizzled 16B chunks ----
    // A[row=w*17+t][kk=i*4+k2] = x[w][i][t+k2]; chunk (kk>>3) stored at chunk^(row&15)
    for (int s = tid; s < ROWS*32; s += 256){
        int row = s >> 5;
        int i   = s & 31;
        int w   = row / TPOS;
        int t   = row - w*TPOS;
        const float* xp = &sX[(w*CEDIM + i)*NCH + t];
        unsigned int lo = (unsigned int)f2bf(xp[0]) | ((unsigned int)f2bf(xp[1]) << 16);
        unsigned int hi = (unsigned int)f2bf(xp[2]) | ((unsigned int)f2bf(xp[3]) << 16);
        int chunk = (i >> 1) ^ (row & 15);
        uint2 val; val.x = lo; val.y = hi;
        *reinterpret_cast<uint2*>(smem + row*256 + chunk*16 + (i & 1)*8) = val;
    }
    __syncthreads();

    // ---- phase 4: stage W tile [128][128] bf16 (overwrites sX region) ----
    {
        const uint4* src = reinterpret_cast<const uint4*>(wbf + chbase*BK);
        for (int s = tid; s < BN*16; s += 256){   // 2048 uint4 chunks
            int r = s >> 4;
            int c = s & 15;
            uint4 v = src[r*16 + c];
            int cs = c ^ (r & 15);
            *reinterpret_cast<uint4*>(smem + 32768 + r*256 + cs*16) = v;
        }
    }
    __syncthreads();

    // ---- phase 5: MFMA. Wave grid 2x2, wave tile 64 rows x 64 channels ----
    const int l  = tid & 63;
    const int wv = tid >> 6;
    const int wy = wv >> 1, wx = wv & 1;
    const int wrow = wy * 64, wcol = wx * 64;
    const int lr = l & 15, lq = l >> 4;

    f32x4 acc[4][4];
    #pragma unroll
    for (int ni = 0; ni < 4; ++ni){
        float bv = bias[chbase + wcol + ni*16 + lr];
        #pragma unroll
        for (int mi = 0; mi < 4; ++mi){
            f32x4 a = {bv, bv, bv, bv};
            acc[mi][ni] = a;
        }
    }

    #pragma unroll
    for (int q = 0; q < 4; ++q){
        bf16x8 af[4], bfr[4];
        const int chunkS = (((q*4 + lq) ^ lr) << 4);  // byte offset of swizzled 16B chunk
        #pragma unroll
        for (int mi = 0; mi < 4; ++mi){
            int row = wrow + mi*16 + lr;
            af[mi] = *reinterpret_cast<const bf16x8*>(smem + row*256 + chunkS);
        }
        #pragma unroll
        for (int ni = 0; ni < 4; ++ni){
            int row = wcol + ni*16 + lr;
            bfr[ni] = *reinterpret_cast<const bf16x8*>(smem + 32768 + row*256 + chunkS);
        }
        #pragma unroll
        for (int mi = 0; mi < 4; ++mi)
            #pragma unroll
            for (int ni = 0; ni < 4; ++ni)
                acc[mi][ni] = __builtin_amdgcn_mfma_f32_16x16x32_bf16(af[mi], bfr[ni], acc[mi][ni], 0, 0, 0);
    }
    __syncthreads();   // all fragment reads done before sY overlay

    // ---- phase 6: C frags -> sY [119][128] f32 ----
    // C/D layout: col = lane&15, row = (lane>>4)*4 + reg
    #pragma unroll
    for (int mi = 0; mi < 4; ++mi){
        int rowb = wrow + mi*16 + lq*4;
        #pragma unroll
        for (int ni = 0; ni < 4; ++ni){
            int col = wcol + ni*16 + lr;
            #pragma unroll
            for (int r = 0; r < 4; ++r){
                if (rowb + r < ROWS) sY[(rowb + r)*BN + col] = acc[mi][ni][r];
            }
        }
    }
    __syncthreads();

    // ---- phase 7: max over 17 positions, coalesced store ----
    for (int o = tid; o < WPB*BN; o += 256){
        int w = o >> 7;
        int c = o & 127;
        int gw = wbase + w;
        if (gw < NWORDS){
            const float* yp = &sY[(w*TPOS)*BN + c];
            float m = yp[0];
            #pragma unroll
            for (int t = 1; t < TPOS; ++t) m = fmaxf(m, yp[t*BN]);
            out[gw*WEDIM + chbase + c] = m;
        }
    }
}

extern "C" void kernel_launch(void* const* d_in, const int* in_sizes, int n_in,
                              void* d_out, int out_size, void* d_ws, size_t ws_size,
                              hipStream_t stream) {
    const float* cemb     = (const float*)d_in[0];   // char_emb_w [256*32]
    const float* cnn      = (const float*)d_in[1];   // cnn_w [512*33*4]
    const int*   data     = (const int*)d_in[2];     // [16384]
    const int*   spelling = (const int*)d_in[3];     // [50000*20]
    float* outp = (float*)d_out;

    unsigned short* wbf = (unsigned short*)d_ws;                 // 131072 B
    float* bias = (float*)((char*)d_ws + WEDIM*BK*sizeof(unsigned short)); // 2048 B

    prep_kernel<<<dim3((WEDIM*BK + WEDIM + 255)/256), dim3(256), 0, stream>>>(cnn, wbf, bias);
    conv_kernel<<<dim3(NWG*4), dim3(256), 0, stream>>>(cemb, data, spelling, wbf, bias, outp);
}

// Round 2
// 154.723 us; speedup vs baseline: 1.3659x; 1.3659x over previous
//
#include <hip/hip_runtime.h>
#include <hip/hip_bf16.h>
#include <cstdint>

// Problem constants
#define NWORDS 16384   // B*S
#define NCH    20      // chars per word
#define CEDIM  32      // char emb dim
#define WEDIM  512     // output channels
#define WPB    8       // words per block
#define NBLK   (NWORDS/WPB)   // 2048

typedef __attribute__((ext_vector_type(8))) short bf16x8;
typedef __attribute__((ext_vector_type(4))) float f32x4;

__device__ __forceinline__ unsigned short f2bf(float f){
    union { float f; unsigned int u; } v; v.f = f;
    unsigned int u = v.u + 0x7fffu + ((v.u >> 16) & 1u);
    return (unsigned short)(u >> 16);
}

// Prep: wbf[o][k*32+i] = bf16(cnn[o][i][k]); cembbf[c][i] = bf16(cemb[c][i]);
// bias[o] = sum_k cnn[o][32][k]
__global__ __launch_bounds__(256) void prep_kernel(const float* __restrict__ cnn,
                                                   const float* __restrict__ cemb,
                                                   unsigned short* __restrict__ wbf,
                                                   unsigned short* __restrict__ cembbf,
                                                   float* __restrict__ bias){
    int idx = blockIdx.x * 256 + threadIdx.x;
    if (idx < WEDIM*128){
        int o = idx >> 7, kk = idx & 127;
        int k = kk >> 5, i = kk & 31;
        wbf[idx] = f2bf(cnn[o*132 + i*4 + k]);
    } else if (idx < WEDIM*128 + 256*CEDIM){
        int j = idx - WEDIM*128;
        cembbf[j] = f2bf(cemb[j]);
    } else if (idx < WEDIM*128 + 256*CEDIM + WEDIM){
        int o = idx - (WEDIM*128 + 256*CEDIM);
        const float* p = cnn + o*132 + 128;
        bias[o] = p[0] + p[1] + p[2] + p[3];
    }
}

__global__ __launch_bounds__(256, 2) void conv_kernel(
    const int* __restrict__ data,            // [16384]
    const int* __restrict__ spelling,        // [50000][20]
    const unsigned short* __restrict__ cembbf, // [256][32] bf16
    const unsigned short* __restrict__ wbf,    // [512][128] bf16 (kk' = k*32+i)
    const float* __restrict__ bias,            // [512]
    float* __restrict__ out)                   // [16384][512] f32
{
    __shared__ int scid[WPB*NCH];
    const int tid   = threadIdx.x;
    const int wbase = blockIdx.x * WPB;

    if (tid < WPB*NCH){
        int w = tid / NCH, j = tid - w*NCH;
        scid[tid] = spelling[data[wbase + w]*NCH + j];
    }
    __syncthreads();

    const int l  = tid & 63;
    const int wv = tid >> 6;
    const int wy = wv >> 1, wx = wv & 1;     // wy: word-half, wx: 32-col half
    const int lr = l & 15, lq = l >> 4;

    // ---- A fragments, loaded once, held in registers ----
    // A-frag layout: lane (lr,lq) holds A[m=lr][kk'=q*32+lq*8+j], j=0..7
    // main tile: row m = t (0..15), word = wy*4+mi; kk'=k*32+i -> k=q, i=lq*8+j
    // => frag = cembbf[scid[w*20 + (t=lr) + (k=q)]][lq*8 .. lq*8+7]
    bf16x8 af[4][4];
    #pragma unroll
    for (int mi = 0; mi < 4; ++mi){
        int w = wy*4 + mi;
        #pragma unroll
        for (int q = 0; q < 4; ++q){
            int ch = scid[w*NCH + lr + q];
            af[mi][q] = *reinterpret_cast<const bf16x8*>(cembbf + ch*CEDIM + lq*8);
        }
    }
    // extra tile (t=16): rows = words 0..7, rows 8..15 zero-padded
    bf16x8 axf[4];
    #pragma unroll
    for (int q = 0; q < 4; ++q){
        int ch = scid[(lr & 7)*NCH + 16 + q];
        bf16x8 v = *reinterpret_cast<const bf16x8*>(cembbf + ch*CEDIM + lq*8);
        if (lr >= 8){ bf16x8 z = {0,0,0,0,0,0,0,0}; v = z; }
        axf[q] = v;
    }

    const int colw = wx*32;   // wave's col base within each 64-col chunk

    // B-frag loader: wave's cols = cc*64 + colw + ni*16 + lr; frag = wbf[col][q*32+lq*8..]
    auto loadB = [&](int cc, bf16x8* dst){
        #pragma unroll
        for (int ni = 0; ni < 2; ++ni){
            const unsigned short* base = wbf + (cc*64 + colw + ni*16 + lr)*128 + lq*8;
            #pragma unroll
            for (int q = 0; q < 4; ++q)
                dst[ni*4+q] = *reinterpret_cast<const bf16x8*>(base + q*32);
        }
    };

    bf16x8 bf0[8], bf1[8];
    loadB(0, bf0);

    #pragma unroll 2
    for (int cc = 0; cc < 8; ++cc){
        bf16x8* bcur = (cc & 1) ? bf1 : bf0;
        bf16x8* bnxt = (cc & 1) ? bf0 : bf1;
        if (cc < 7) loadB(cc+1, bnxt);

        float bv0 = bias[cc*64 + colw + lr];
        float bv1 = bias[cc*64 + colw + 16 + lr];

        f32x4 acc[4][2], accX[2];
        {
            f32x4 z = {0.f, 0.f, 0.f, 0.f};
            accX[0] = z; accX[1] = z;
            #pragma unroll
            for (int mi = 0; mi < 4; ++mi){ acc[mi][0] = z; acc[mi][1] = z; }
        }

        #pragma unroll
        for (int q = 0; q < 4; ++q){
            #pragma unroll
            for (int ni = 0; ni < 2; ++ni){
                #pragma unroll
                for (int mi = 0; mi < 4; ++mi)
                    acc[mi][ni] = __builtin_amdgcn_mfma_f32_16x16x32_bf16(
                        af[mi][q], bcur[ni*4+q], acc[mi][ni], 0, 0, 0);
                accX[ni] = __builtin_amdgcn_mfma_f32_16x16x32_bf16(
                        axf[q], bcur[ni*4+q], accX[ni], 0, 0, 0);
            }
        }

        // ---- epilogue: max over t, in registers ----
        // C layout: col = lr, row t = lq*4 + reg; extra tile: row (=word) = lq*4+reg
        #pragma unroll
        for (int mi = 0; mi < 4; ++mi){
            int w = wy*4 + mi;
            float m0 = fmaxf(fmaxf(acc[mi][0][0], acc[mi][0][1]),
                             fmaxf(acc[mi][0][2], acc[mi][0][3]));
            float m1 = fmaxf(fmaxf(acc[mi][1][0], acc[mi][1][1]),
                             fmaxf(acc[mi][1][2], acc[mi][1][3]));
            // fold t=16: word w's t16 value lives in lanes with lq==wy, reg mi
            if (lq == wy){
                m0 = fmaxf(m0, accX[0][mi]);
                m1 = fmaxf(m1, accX[1][mi]);
            }
            m0 = fmaxf(m0, __shfl_xor(m0, 16, 64));
            m0 = fmaxf(m0, __shfl_xor(m0, 32, 64));
            m1 = fmaxf(m1, __shfl_xor(m1, 16, 64));
            m1 = fmaxf(m1, __shfl_xor(m1, 32, 64));
            m0 += bv0;
            m1 += bv1;
            if (lq < 2){
                float mv = lq ? m1 : m0;
                out[(wbase + w)*WEDIM + cc*64 + colw + lq*16 + lr] = mv;
            }
        }
    }
}

extern "C" void kernel_launch(void* const* d_in, const int* in_sizes, int n_in,
                              void* d_out, int out_size, void* d_ws, size_t ws_size,
                              hipStream_t stream) {
    const float* cemb     = (const float*)d_in[0];   // char_emb_w [256*32]
    const float* cnn      = (const float*)d_in[1];   // cnn_w [512*33*4]
    const int*   data     = (const int*)d_in[2];     // [16384]
    const int*   spelling = (const int*)d_in[3];     // [50000*20]
    float* outp = (float*)d_out;

    unsigned short* wbf    = (unsigned short*)d_ws;                       // 131072 B
    float*          bias   = (float*)((char*)d_ws + 131072);              // 2048 B
    unsigned short* cembbf = (unsigned short*)((char*)d_ws + 133120);     // 16384 B

    int prep_items = WEDIM*128 + 256*CEDIM + WEDIM;
    prep_kernel<<<dim3((prep_items + 255)/256), dim3(256), 0, stream>>>(cnn, cemb, wbf, cembbf, bias);
    conv_kernel<<<dim3(NBLK), dim3(256), 0, stream>>>(data, spelling, cembbf, wbf, bias, outp);
}

// Round 3
// 149.081 us; speedup vs baseline: 1.4175x; 1.0378x over previous
//
#include <hip/hip_runtime.h>
#include <hip/hip_bf16.h>
#include <cstdint>

// Problem constants
#define NWORDS 16384   // B*S
#define NCH    20      // chars per word
#define CEDIM  32      // char emb dim
#define WEDIM  512     // output channels
#define WPB    8       // words per block
#define NBLK   (NWORDS/WPB)   // 2048

typedef __attribute__((ext_vector_type(8))) short bf16x8;
typedef __attribute__((ext_vector_type(4))) float f32x4;

__device__ __forceinline__ unsigned short f2bf(float f){
    union { float f; unsigned int u; } v; v.f = f;
    unsigned int u = v.u + 0x7fffu + ((v.u >> 16) & 1u);
    return (unsigned short)(u >> 16);
}

// Prep: wbf[o][k*32+i] = bf16(cnn[o][i][k]); cembbf[c][i] = bf16(cemb[c][i]);
// bias[o] = sum_k cnn[o][32][k]
__global__ __launch_bounds__(256) void prep_kernel(const float* __restrict__ cnn,
                                                   const float* __restrict__ cemb,
                                                   unsigned short* __restrict__ wbf,
                                                   unsigned short* __restrict__ cembbf,
                                                   float* __restrict__ bias){
    int idx = blockIdx.x * 256 + threadIdx.x;
    if (idx < WEDIM*128){
        int o = idx >> 7, kk = idx & 127;
        int k = kk >> 5, i = kk & 31;
        wbf[idx] = f2bf(cnn[o*132 + i*4 + k]);
    } else if (idx < WEDIM*128 + 256*CEDIM){
        int j = idx - WEDIM*128;
        cembbf[j] = f2bf(cemb[j]);
    } else if (idx < WEDIM*128 + 256*CEDIM + WEDIM){
        int o = idx - (WEDIM*128 + 256*CEDIM);
        const float* p = cnn + o*132 + 128;
        bias[o] = p[0] + p[1] + p[2] + p[3];
    }
}

// waves_per_eu(2,2): pin exactly 2 waves/SIMD -> 256 VGPR budget/wave.
// Live set ~214 VGPR (af 64 + axf 16 + B dbuf 64 + acc 40 + bias 16 + addr):
// fits with zero spill. Round-2's compiler chose 108 VGPRs and spilled the
// A-fragments to scratch (FETCH_SIZE 2.2 GB vs ~50 MB real footprint).
__global__ __attribute__((amdgpu_waves_per_eu(2,2))) __launch_bounds__(256)
void conv_kernel(
    const int* __restrict__ data,            // [16384]
    const int* __restrict__ spelling,        // [50000][20]
    const unsigned short* __restrict__ cembbf, // [256][32] bf16
    const unsigned short* __restrict__ wbf,    // [512][128] bf16 (kk' = k*32+i)
    const float* __restrict__ bias,            // [512]
    float* __restrict__ out)                   // [16384][512] f32
{
    __shared__ int scid[WPB*NCH];
    const int tid   = threadIdx.x;
    const int wbase = blockIdx.x * WPB;

    if (tid < WPB*NCH){
        int w = tid / NCH, j = tid - w*NCH;
        scid[tid] = spelling[data[wbase + w]*NCH + j];
    }
    __syncthreads();

    const int l  = tid & 63;
    const int wv = tid >> 6;
    const int wy = wv >> 1, wx = wv & 1;     // wy: word-half, wx: 32-col half
    const int lr = l & 15, lq = l >> 4;

    // ---- A fragments, loaded once, held in registers ----
    // lane (lr,lq) holds A[m=lr][kk'=q*32+lq*8+j]; kk'=k*32+i -> k=q, i=lq*8+j
    // => frag = cembbf[scid[w*20 + (t=lr) + (k=q)]][lq*8 .. lq*8+7]
    bf16x8 af[4][4];
    #pragma unroll
    for (int mi = 0; mi < 4; ++mi){
        int w = wy*4 + mi;
        #pragma unroll
        for (int q = 0; q < 4; ++q){
            int ch = scid[w*NCH + lr + q];
            af[mi][q] = *reinterpret_cast<const bf16x8*>(cembbf + ch*CEDIM + lq*8);
        }
    }
    // extra tile (t=16): rows = words 0..7, rows 8..15 zero-padded
    bf16x8 axf[4];
    #pragma unroll
    for (int q = 0; q < 4; ++q){
        int ch = scid[(lr & 7)*NCH + 16 + q];
        bf16x8 v = *reinterpret_cast<const bf16x8*>(cembbf + ch*CEDIM + lq*8);
        if (lr >= 8){ bf16x8 z = {0,0,0,0,0,0,0,0}; v = z; }
        axf[q] = v;
    }

    const int colw = wx*32;   // wave's col base within each 64-col chunk

    // Preload all per-cc bias values (L1-hot, but removes epilogue bubbles)
    float bv0[8], bv1[8];
    #pragma unroll
    for (int cc = 0; cc < 8; ++cc){
        bv0[cc] = bias[cc*64 + colw + lr];
        bv1[cc] = bias[cc*64 + colw + 16 + lr];
    }

    // B-frag loader: wave's cols = cc*64 + colw + ni*16 + lr; frag = wbf[col][q*32+lq*8..]
    auto loadB = [&](int cc, bf16x8* dst){
        #pragma unroll
        for (int ni = 0; ni < 2; ++ni){
            const unsigned short* base = wbf + (cc*64 + colw + ni*16 + lr)*128 + lq*8;
            #pragma unroll
            for (int q = 0; q < 4; ++q)
                dst[ni*4+q] = *reinterpret_cast<const bf16x8*>(base + q*32);
        }
    };

    bf16x8 bf0[8], bf1[8];
    loadB(0, bf0);

    #pragma unroll 2
    for (int cc = 0; cc < 8; ++cc){
        bf16x8* bcur = (cc & 1) ? bf1 : bf0;
        bf16x8* bnxt = (cc & 1) ? bf0 : bf1;
        if (cc < 7) loadB(cc+1, bnxt);

        f32x4 acc[4][2], accX[2];
        {
            f32x4 z = {0.f, 0.f, 0.f, 0.f};
            accX[0] = z; accX[1] = z;
            #pragma unroll
            for (int mi = 0; mi < 4; ++mi){ acc[mi][0] = z; acc[mi][1] = z; }
        }

        #pragma unroll
        for (int q = 0; q < 4; ++q){
            #pragma unroll
            for (int ni = 0; ni < 2; ++ni){
                #pragma unroll
                for (int mi = 0; mi < 4; ++mi)
                    acc[mi][ni] = __builtin_amdgcn_mfma_f32_16x16x32_bf16(
                        af[mi][q], bcur[ni*4+q], acc[mi][ni], 0, 0, 0);
                accX[ni] = __builtin_amdgcn_mfma_f32_16x16x32_bf16(
                        axf[q], bcur[ni*4+q], accX[ni], 0, 0, 0);
            }
        }

        // ---- epilogue: max over t, in registers ----
        // C layout: col = lr, row t = lq*4 + reg; extra tile: row (=word) = lq*4+reg
        #pragma unroll
        for (int mi = 0; mi < 4; ++mi){
            int w = wy*4 + mi;
            float m0 = fmaxf(fmaxf(acc[mi][0][0], acc[mi][0][1]),
                             fmaxf(acc[mi][0][2], acc[mi][0][3]));
            float m1 = fmaxf(fmaxf(acc[mi][1][0], acc[mi][1][1]),
                             fmaxf(acc[mi][1][2], acc[mi][1][3]));
            // fold t=16: word w's t16 value lives in lanes with lq==wy, reg mi
            if (lq == wy){
                m0 = fmaxf(m0, accX[0][mi]);
                m1 = fmaxf(m1, accX[1][mi]);
            }
            m0 = fmaxf(m0, __shfl_xor(m0, 16, 64));
            m0 = fmaxf(m0, __shfl_xor(m0, 32, 64));
            m1 = fmaxf(m1, __shfl_xor(m1, 16, 64));
            m1 = fmaxf(m1, __shfl_xor(m1, 32, 64));
            m0 += bv0[cc];
            m1 += bv1[cc];
            if (lq < 2){
                float mv = lq ? m1 : m0;
                __builtin_nontemporal_store(
                    mv, &out[(wbase + w)*WEDIM + cc*64 + colw + lq*16 + lr]);
            }
        }
    }
}

extern "C" void kernel_launch(void* const* d_in, const int* in_sizes, int n_in,
                              void* d_out, int out_size, void* d_ws, size_t ws_size,
                              hipStream_t stream) {
    const float* cemb     = (const float*)d_in[0];   // char_emb_w [256*32]
    const float* cnn      = (const float*)d_in[1];   // cnn_w [512*33*4]
    const int*   data     = (const int*)d_in[2];     // [16384]
    const int*   spelling = (const int*)d_in[3];     // [50000*20]
    float* outp = (float*)d_out;

    unsigned short* wbf    = (unsigned short*)d_ws;                       // 131072 B
    float*          bias   = (float*)((char*)d_ws + 131072);              // 2048 B
    unsigned short* cembbf = (unsigned short*)((char*)d_ws + 133120);     // 16384 B

    int prep_items = WEDIM*128 + 256*CEDIM + WEDIM;
    prep_kernel<<<dim3((prep_items + 255)/256), dim3(256), 0, stream>>>(cnn, cemb, wbf, cembbf, bias);
    conv_kernel<<<dim3(NBLK), dim3(256), 0, stream>>>(data, spelling, cembbf, wbf, bias, outp);
}